// Round 9
// baseline (192.714 us; speedup 1.0000x reference)
//
#include <hip/hip_runtime.h>
#include <math.h>

// DynamicRelationModeler: x=concat(img,txt) [512x512]; per r: a=x@Wl_r^T, b=x@Wr_r^T;
// h=a_i+b_j+b1_r; LN over H; s=relu(hn)@w2_r+b2_r; argmax/max over r; mask.
//
// Round-9: K0 back to fp32 (r5's validated k0_gemm). r8 showed split-bf16 K0
// puts ~1.5e-5 error on scores -> argmax flips (Output2 err 1.0). K2 stays on
// MFMA: its dot only perturbs Sv at ~4e-7 rel (enters var as d/256/var), the
// same order as the always-passing fp32 path. conv2 + k2_mfma are the
// r8-functionally-validated versions. K1/K3/K4 byte-identical to round 5.
//
// ws layout (floats):
//   Aarr [4][512][512]  a_r[i][h]            (OFF_A)
//   Barr [4][512][512]  b'_r[j][h]           (OFF_B)
//   dotp [2][4][512][512]  k-split dots      (OFF_DOT)
//   Spart[2][4][512][512]  k-split scores    (OFF_S)
//   ma/qa/mb/qb [4][512], G, BW, SA, SB, CB  (tail)
// Alias (live range disjoint, stream-ordered):
//   AH/AL/BH/BL [4][512][512] ush @ OFF_S    (conv2 .. k2_mfma; k3 overwrites)

typedef __attribute__((ext_vector_type(8))) short s8b;            // 8 x bf16
typedef __attribute__((ext_vector_type(4))) float f32x4;
typedef __attribute__((ext_vector_type(4))) unsigned short us4;

namespace {
constexpr size_t PLANE  = 512 * 512;            // 262144
constexpr size_t OFF_A   = 0;
constexpr size_t OFF_B   = OFF_A + 4 * PLANE;   // 1048576
constexpr size_t OFF_DOT = OFF_B + 4 * PLANE;   // 2097152
constexpr size_t OFF_S   = OFF_DOT + 8 * PLANE; // 4194304
constexpr size_t OFF_MA  = OFF_S + 8 * PLANE;   // 6291456
constexpr size_t OFF_QA  = OFF_MA + 2048;
constexpr size_t OFF_MB  = OFF_QA + 2048;
constexpr size_t OFF_QB  = OFF_MB + 2048;
constexpr size_t OFF_G   = OFF_QB + 2048;       // gamma [2048]
constexpr size_t OFF_BW  = OFF_G + 2048;        // (beta, w2/2) [2048][2]
constexpr size_t OFF_SA  = OFF_BW + 4096;       // [2048]
constexpr size_t OFF_SB  = OFF_SA + 2048;       // [2048]
constexpr size_t OFF_CB  = OFF_SB + 2048;       // [4]  (ws end: same as r5)
}

__device__ __forceinline__ unsigned short bf16rne(float v) {
  const unsigned u = __float_as_uint(v);
  return (unsigned short)((u + 0x7fffu + ((u >> 16) & 1u)) >> 16);
}

__device__ __forceinline__ f32x4 mfma16(s8b a, s8b b, f32x4 c) {
  return __builtin_amdgcn_mfma_f32_16x16x32_bf16(a, b, c, 0, 0, 0);
}

// ---------------- K0: input GEMM  C[n][4096] = x @ [Wl|Wr]^T ----------------
// grid 512 = 8 i-tiles x 64 col-tiles; block 256 (16x16 threads, 4x4 reg tile)
// (r5 fp32 version: a/b must be fp32-exact for exact argmax)
__global__ __launch_bounds__(256) void k0_gemm(const float* __restrict__ img,
                                               const float* __restrict__ txt,
                                               const float* __restrict__ W1,
                                               const float* __restrict__ b1,
                                               float* __restrict__ ws) {
  const int b = blockIdx.x;
  const int it = b >> 6;
  const int ct = b & 63;
  const int which = ct >> 5;      // 0 -> a (Wl), 1 -> b (Wr)
  const int r = (ct >> 3) & 3;
  const int ht = ct & 7;
  const int i0 = it << 6, h0 = ht << 6;
  const int t = threadIdx.x;
  const int tx = t & 15, ty = t >> 4;

  __shared__ float Xs[16 * 68];   // [k][i], pitch 68 -> 16B-aligned rows for b128 reads
  __shared__ float Wsm[16 * 68];  // [k][h]

  float acc[16], pacc[16];
#pragma unroll
  for (int p = 0; p < 16; ++p) { acc[p] = 0.f; pacc[p] = 0.f; }

  const int srow = t >> 2;
  const int sf4 = (t & 3) << 2;
  const int xi = i0 + srow;
  const float* xrow = (xi < 256) ? (img + (size_t)xi * 512)
                                 : (txt + (size_t)(xi - 256) * 512);
  const float* wrow = W1 + (size_t)(r * 512 + h0 + srow) * 1024 + which * 512;

  for (int k0 = 0; k0 < 512; k0 += 16) {
    const float4 xv = *(const float4*)(xrow + k0 + sf4);
    const float4 wv = *(const float4*)(wrow + k0 + sf4);
    __syncthreads();
    Xs[(sf4 + 0) * 68 + srow] = xv.x;
    Xs[(sf4 + 1) * 68 + srow] = xv.y;
    Xs[(sf4 + 2) * 68 + srow] = xv.z;
    Xs[(sf4 + 3) * 68 + srow] = xv.w;
    Wsm[(sf4 + 0) * 68 + srow] = wv.x;
    Wsm[(sf4 + 1) * 68 + srow] = wv.y;
    Wsm[(sf4 + 2) * 68 + srow] = wv.z;
    Wsm[(sf4 + 3) * 68 + srow] = wv.w;
    __syncthreads();
#pragma unroll
    for (int k = 0; k < 16; ++k) {
      const float4 a4 = *(const float4*)&Xs[k * 68 + 4 * ty];
      const float4 b4 = *(const float4*)&Wsm[k * 68 + 4 * tx];
      const float av[4] = {a4.x, a4.y, a4.z, a4.w};
      const float bv[4] = {b4.x, b4.y, b4.z, b4.w};
#pragma unroll
      for (int c = 0; c < 4; ++c)
#pragma unroll
        for (int d = 0; d < 4; ++d)
          pacc[c * 4 + d] = fmaf(av[c], bv[d], pacc[c * 4 + d]);
    }
    // fold per-stage partial into master (split accumulation: ~1e-7 error)
#pragma unroll
    for (int p = 0; p < 16; ++p) { acc[p] += pacc[p]; pacc[p] = 0.f; }
  }

  float4 bb = make_float4(0.f, 0.f, 0.f, 0.f);
  if (which) bb = *(const float4*)(b1 + r * 512 + h0 + 4 * tx);
  float* dst = ws + (which ? OFF_B : OFF_A) + (size_t)r * PLANE;
#pragma unroll
  for (int c = 0; c < 4; ++c) {
    float4 v;
    v.x = acc[c * 4 + 0] + bb.x;
    v.y = acc[c * 4 + 1] + bb.y;
    v.z = acc[c * 4 + 2] + bb.z;
    v.w = acc[c * 4 + 3] + bb.w;
    *(float4*)(dst + (size_t)(i0 + 4 * ty + c) * 512 + h0 + 4 * tx) = v;
  }
}

// ---------------- conv2: A/B fp32 planes -> AH/AL/BH/BL bf16 @ OFF_S ----------------
// grid 2048 x 256 over 524288 float4 (A planes then B planes, contiguous)
__global__ __launch_bounds__(256) void k_conv2(float* __restrict__ ws) {
  const int idx = blockIdx.x * 256 + threadIdx.x;
  const float4 v = *(const float4*)(ws + (size_t)idx * 4);
  unsigned short* SH = (unsigned short*)(ws + OFF_S);
  unsigned short *dh, *dl;
  if (idx < 262144) {           // A planes
    const size_t e = (size_t)idx * 4;
    dh = SH + e;                 dl = SH + 4 * PLANE + e;
  } else {                      // B planes
    const size_t e = (size_t)idx * 4 - 4 * PLANE;
    dh = SH + 8 * PLANE + e;     dl = SH + 12 * PLANE + e;
  }
  const float vv[4] = {v.x, v.y, v.z, v.w};
  us4 h4, l4;
#pragma unroll
  for (int c = 0; c < 4; ++c) {
    const unsigned short hh = bf16rne(vv[c]);
    h4[c] = hh;
    l4[c] = bf16rne(vv[c] - __uint_as_float(((unsigned)hh) << 16));
  }
  *(us4*)dh = h4;
  *(us4*)dl = l4;
}

// ---------------- K1: row stats + relu-linear row sums + packing ----------------
// one wave per (which, r, row); grid 1024 x 256.  (unchanged from r5)
__global__ __launch_bounds__(256) void k1_stats(float* __restrict__ ws,
                                                const float* __restrict__ gamma,
                                                const float* __restrict__ beta,
                                                const float* __restrict__ w2) {
  const int t = threadIdx.x;
  const int gw = (blockIdx.x * 256 + t) >> 6;  // 0..4095
  const int lane = t & 63;
  const int which = gw >> 11;
  const int rr = (gw >> 9) & 3;
  const int row = gw & 511;
  const float* src =
      ws + (which ? OFF_B : OFF_A) + (size_t)(rr * 512 + row) * 512 + lane * 8;
  const float* gsrc = gamma + rr * 512 + lane * 8;
  const float* wsrc = w2 + rr * 512 + lane * 8;
  float s = 0.f, q = 0.f, sa = 0.f, cgs = 0.f;
#pragma unroll
  for (int c = 0; c < 2; ++c) {
    const float4 v = *(const float4*)(src + c * 4);
    const float4 g = *(const float4*)(gsrc + c * 4);
    const float4 w = *(const float4*)(wsrc + c * 4);
    s += v.x + v.y + v.z + v.w;
    q += v.x * v.x + v.y * v.y + v.z * v.z + v.w * v.w;
    const float cgx = 0.5f * w.x * g.x;
    const float cgy = 0.5f * w.y * g.y;
    const float cgz = 0.5f * w.z * g.z;
    const float cgw = 0.5f * w.w * g.w;
    sa += cgx * v.x + cgy * v.y + cgz * v.z + cgw * v.w;
    cgs += cgx + cgy + cgz + cgw;
  }
#pragma unroll
  for (int off = 32; off >= 1; off >>= 1) {
    s += __shfl_down(s, off, 64);
    q += __shfl_down(q, off, 64);
    sa += __shfl_down(sa, off, 64);
    cgs += __shfl_down(cgs, off, 64);
  }
  if (lane == 0) {
    const float ma = s * (1.f / 512.f);
    ws[(which ? OFF_MB : OFF_MA) + rr * 512 + row] = ma;
    ws[(which ? OFF_QB : OFF_QA) + rr * 512 + row] = q;
    ws[(which ? OFF_SB : OFF_SA) + rr * 512 + row] = sa - ma * cgs;
  }
  if (blockIdx.x < 8) {
    const int idx = blockIdx.x * 256 + t;  // 0..2047 == r*512+k
    ws[OFF_G + idx] = gamma[idx];
    float2 bw;
    bw.x = beta[idx];
    bw.y = 0.5f * w2[idx];    // c = w2/2
    *(float2*)(ws + OFF_BW + (size_t)idx * 2) = bw;
  }
  if (blockIdx.x == 8) {
    const int rb = t >> 6;   // 0..3
    float cb = 0.f;
#pragma unroll
    for (int c = 0; c < 8; ++c)
      cb += 0.5f * w2[rb * 512 + lane * 8 + c] * beta[rb * 512 + lane * 8 + c];
#pragma unroll
    for (int off = 32; off >= 1; off >>= 1) cb += __shfl_down(cb, off, 64);
    if (lane == 0) ws[OFF_CB + rb] = cb;
  }
}

// ---------------- K2 (MFMA): dotp[ks][r][i][j] = sum_k a.b' ----------------
// grid 512 = 8jt x 8it x 4r x 2ks; block 256 = 4 waves, each wave 32x32.
// Split-bf16, 3 products; dot error ~2e-4 -> Sv rel err ~4e-7 (argmax-safe).
__global__ __launch_bounds__(256) void k2_mfma(float* __restrict__ ws) {
  const int b = blockIdx.x;
  const int jt = b & 7, it = (b >> 3) & 7, r = (b >> 6) & 3, ks = b >> 8;
  const int i0 = it << 6, j0 = jt << 6;
  const int kb = ks << 8;
  const int t = threadIdx.x, w = t >> 6, l = t & 63;
  const int wr = w >> 1, wc = w & 1;
  const int lrow = l & 15, lk = (l >> 4) << 3;

  const unsigned short* SH = (const unsigned short*)(ws + OFF_S);
  const unsigned short* AH = SH;
  const unsigned short* AL = SH + 4 * PLANE;
  const unsigned short* BH = SH + 8 * PLANE;
  const unsigned short* BL = SH + 12 * PLANE;

  const int ia = i0 + wr * 32 + lrow;
  const int jb = j0 + wc * 32 + lrow;
  const size_t ar0 = (size_t)(r * 512 + ia) * 512 + kb + lk;
  const size_t ar1 = ar0 + 16 * 512;
  const size_t br0 = (size_t)(r * 512 + jb) * 512 + kb + lk;
  const size_t br1 = br0 + 16 * 512;

  f32x4 acc00 = {0.f, 0.f, 0.f, 0.f}, acc01 = acc00, acc10 = acc00, acc11 = acc00;

#pragma unroll
  for (int k0 = 0; k0 < 256; k0 += 32) {
    const s8b ah0 = *(const s8b*)(AH + ar0 + k0);
    const s8b ah1 = *(const s8b*)(AH + ar1 + k0);
    const s8b al0 = *(const s8b*)(AL + ar0 + k0);
    const s8b al1 = *(const s8b*)(AL + ar1 + k0);
    const s8b bh0 = *(const s8b*)(BH + br0 + k0);
    const s8b bh1 = *(const s8b*)(BH + br1 + k0);
    const s8b bl0 = *(const s8b*)(BL + br0 + k0);
    const s8b bl1 = *(const s8b*)(BL + br1 + k0);
    acc00 = mfma16(ah0, bh0, acc00);
    acc00 = mfma16(ah0, bl0, acc00);
    acc00 = mfma16(al0, bh0, acc00);
    acc01 = mfma16(ah0, bh1, acc01);
    acc01 = mfma16(ah0, bl1, acc01);
    acc01 = mfma16(al0, bh1, acc01);
    acc10 = mfma16(ah1, bh0, acc10);
    acc10 = mfma16(ah1, bl0, acc10);
    acc10 = mfma16(al1, bh0, acc10);
    acc11 = mfma16(ah1, bh1, acc11);
    acc11 = mfma16(ah1, bl1, acc11);
    acc11 = mfma16(al1, bh1, acc11);
  }

  float* dst = ws + OFF_DOT + (size_t)ks * (4 * PLANE) + (size_t)r * PLANE;
  const int rb = i0 + wr * 32 + ((l >> 4) << 2);
  const int cb = j0 + wc * 32 + lrow;
#pragma unroll
  for (int v = 0; v < 4; ++v) {
    dst[(size_t)(rb + v) * 512 + cb]           = acc00[v];
    dst[(size_t)(rb + v) * 512 + cb + 16]      = acc01[v];
    dst[(size_t)(rb + 16 + v) * 512 + cb]      = acc10[v];
    dst[(size_t)(rb + 16 + v) * 512 + cb + 16] = acc11[v];
  }
}

// ---------------- K3: score kernel v6 (abs-trick, 3-op inner) ----------------
// (unchanged from r5)
__global__ __launch_bounds__(256) void k3_score(float* __restrict__ ws) {
  const int b = blockIdx.x;
  const int jt = b & 15, it = (b >> 4) & 7, r = (b >> 7) & 3, ks = b >> 9;
  const int i0 = it << 6, j0 = jt << 5;
  const int t = threadIdx.x;
  const int tx = t & 15, ty = t >> 4;

  __shared__ float As2[64 * 68];  // [k][i-row swizzled], 64 rows, pitch 68
  __shared__ float Bs2[64 * 36];  // [k][j-row swizzled], 32 rows, pitch 36
  __shared__ float bwS[64 * 2];   // (beta, c) per k of current chunk

  const float4 mav = *(const float4*)(ws + OFF_MA + r * 512 + i0 + 4 * ty);
  const float4 qav = *(const float4*)(ws + OFF_QA + r * 512 + i0 + 4 * ty);
  const float2 mbv = *(const float2*)(ws + OFF_MB + r * 512 + j0 + 2 * tx);
  const float2 qbv = *(const float2*)(ws + OFF_QB + r * 512 + j0 + 2 * tx);
  const float4 sav = *(const float4*)(ws + OFF_SA + r * 512 + i0 + 4 * ty);
  const float2 sbv = *(const float2*)(ws + OFF_SB + r * 512 + j0 + 2 * tx);
  const float cbr = ws[OFF_CB + r];
  const float mavA[4] = {mav.x, mav.y, mav.z, mav.w};
  const float qavA[4] = {qav.x, qav.y, qav.z, qav.w};
  const float savA[4] = {sav.x, sav.y, sav.z, sav.w};
  const float mbA[2] = {mbv.x, mbv.y};
  const float qbA[2] = {qbv.x, qbv.y};
  const float sbA[2] = {sbv.x, sbv.y};
  float Sv[8], acc[8];
#pragma unroll
  for (int c = 0; c < 4; ++c) {
    const size_t doff = (size_t)r * PLANE + (size_t)(i0 + 4 * ty + c) * 512 + j0 + 2 * tx;
    const float2 d0 = *(const float2*)(ws + OFF_DOT + doff);
    const float2 d1 = *(const float2*)(ws + OFF_DOT + 4 * PLANE + doff);
    const float dA[2] = {d0.x + d1.x, d0.y + d1.y};
#pragma unroll
    for (int d = 0; d < 2; ++d) {
      const int p = c * 2 + d;
      const float mu = mavA[c] + mbA[d];
      const float msq = (qavA[c] + qbA[d] + 2.f * dA[d]) * (1.f / 512.f);
      const float var = msq - mu * mu;
      Sv[p] = 1.0f / sqrtf(var + 1e-5f);   // precise (no fast-math)
      acc[p] = (ks == 0) ? fmaf(Sv[p], savA[c] + sbA[d], cbr) : 0.f;
    }
  }

  const int kbase = ks << 8;
  const int srow = ty;              // 0..15
  const int sf4 = tx << 2;          // 0..60; (k>>2)&7 == tx&7 for staged k
  const int sblk = tx & 7;
  float maR[4], mbR[2];
#pragma unroll
  for (int c2 = 0; c2 < 4; ++c2)
    maR[c2] = ws[OFF_MA + r * 512 + i0 + srow + 16 * c2];
#pragma unroll
  for (int c2 = 0; c2 < 2; ++c2)
    mbR[c2] = ws[OFF_MB + r * 512 + j0 + srow + 16 * c2];

  float4 aC[4], bC[2], gC;
  float2 bwC = make_float2(0.f, 0.f);
  {
    const int kb = kbase;
    gC = *(const float4*)(ws + OFF_G + r * 512 + kb + sf4);
#pragma unroll
    for (int c2 = 0; c2 < 4; ++c2)
      aC[c2] = *(const float4*)(ws + OFF_A + (size_t)(r * 512 + i0 + srow + 16 * c2) * 512 + kb + sf4);
#pragma unroll
    for (int c2 = 0; c2 < 2; ++c2)
      bC[c2] = *(const float4*)(ws + OFF_B + (size_t)(r * 512 + j0 + srow + 16 * c2) * 512 + kb + sf4);
    if (t < 64) bwC = *(const float2*)(ws + OFF_BW + (size_t)(r * 512 + kb + t) * 2);
  }

#pragma unroll
  for (int kc = 0; kc < 4; ++kc) {
    __syncthreads();  // previous chunk's LDS reads complete before overwrite
    {
      const float ga[4] = {gC.x, gC.y, gC.z, gC.w};
#pragma unroll
      for (int c2 = 0; c2 < 4; ++c2) {
        const int row = srow + 16 * c2;
        const int off = (((row >> 2) ^ sblk) << 2) + (row & 3);
        const float aq[4] = {aC[c2].x, aC[c2].y, aC[c2].z, aC[c2].w};
#pragma unroll
        for (int q = 0; q < 4; ++q)
          As2[(sf4 + q) * 68 + off] = (aq[q] - maR[c2]) * ga[q];
      }
#pragma unroll
      for (int c2 = 0; c2 < 2; ++c2) {
        const int row = srow + 16 * c2;
        const int off = (((row >> 2) ^ sblk) << 2) + (row & 3);
        const float bq[4] = {bC[c2].x, bC[c2].y, bC[c2].z, bC[c2].w};
#pragma unroll
        for (int q = 0; q < 4; ++q)
          Bs2[(sf4 + q) * 36 + off] = (bq[q] - mbR[c2]) * ga[q];
      }
      if (t < 64) *(float2*)(bwS + 2 * t) = bwC;
    }
    if (kc < 3) {
      const int kb = kbase + ((kc + 1) << 6);
      gC = *(const float4*)(ws + OFF_G + r * 512 + kb + sf4);
#pragma unroll
      for (int c2 = 0; c2 < 4; ++c2)
        aC[c2] = *(const float4*)(ws + OFF_A + (size_t)(r * 512 + i0 + srow + 16 * c2) * 512 + kb + sf4);
#pragma unroll
      for (int c2 = 0; c2 < 2; ++c2)
        bC[c2] = *(const float4*)(ws + OFF_B + (size_t)(r * 512 + j0 + srow + 16 * c2) * 512 + kb + sf4);
      if (t < 64) bwC = *(const float2*)(ws + OFF_BW + (size_t)(r * 512 + kb + t) * 2);
    }
    __syncthreads();  // staged data visible

    float cacc[8];
#pragma unroll
    for (int p = 0; p < 8; ++p) cacc[p] = 0.f;

#pragma unroll 4
    for (int k = 0; k < 64; ++k) {
      const int K = (k >> 2) & 7;
      const float4 aA = *(const float4*)&As2[k * 68 + ((ty ^ K) << 2)];  // b128
      const float2 bB = *(const float2*)&Bs2[k * 36 + (((tx >> 1) ^ K) << 2) + ((tx & 1) << 1)];  // b64
      const float2 bw = *(const float2*)&bwS[2 * k];                     // b64 broadcast
      const float aq[4] = {aA.x, aA.y, aA.z, aA.w};
      const float bq[2] = {bB.x, bB.y};
#pragma unroll
      for (int c = 0; c < 4; ++c)
#pragma unroll
        for (int d = 0; d < 2; ++d) {
          const int p = c * 2 + d;
          const float u = aq[c] + bq[d];               // (a-ma)g + (b-mb)g
          const float hn = fmaf(u, Sv[p], bw.x);       // *Sv + beta
          cacc[p] = fmaf(bw.y, fabsf(hn), cacc[p]);    // += c*|hn|  (abs free)
        }
    }
#pragma unroll
    for (int p = 0; p < 8; ++p) acc[p] += cacc[p];
  }

  float* dst = ws + OFF_S + (size_t)ks * (4 * PLANE) + (size_t)r * PLANE;
#pragma unroll
  for (int c = 0; c < 4; ++c) {
    float2 v;
    v.x = acc[c * 2 + 0];
    v.y = acc[c * 2 + 1];
    *(float2*)(dst + (size_t)(i0 + 4 * ty + c) * 512 + j0 + 2 * tx) = v;
  }
}

// ---------------- K4: combine + outputs ---------------- (unchanged)
__global__ __launch_bounds__(256) void k4_combine(const float* __restrict__ ws,
                                                  const float* __restrict__ img,
                                                  const float* __restrict__ txt,
                                                  const float* __restrict__ b2,
                                                  float* __restrict__ out) {
  const int idx = blockIdx.x * 256 + threadIdx.x;  // 0..262143
  const int i = idx >> 9, j = idx & 511;
  const float* s0 = ws + OFF_S;
  const float* s1 = ws + OFF_S + 4 * PLANE;
  float best = -3.4e38f;
  int rel = 0;
#pragma unroll
  for (int r = 0; r < 4; ++r) {
    const float s = s0[r * PLANE + idx] + s1[r * PLANE + idx] + b2[r];
    if (s > best) { best = s; rel = r; }  // strict > == first-index argmax
  }
  out[idx] = (i < 256) ? img[idx] : txt[idx - 131072];
  out[PLANE + idx] = best;
  out[2 * PLANE + idx] = (float)rel;
  // match numpy: float32 best promoted to double vs python-float 0.2
  out[3 * PLANE + idx] = (i != j && (double)best > 0.2) ? 1.0f : 0.0f;
}

extern "C" void kernel_launch(void* const* d_in, const int* in_sizes, int n_in,
                              void* d_out, int out_size, void* d_ws, size_t ws_size,
                              hipStream_t stream) {
  const float* img   = (const float*)d_in[0];
  const float* txt   = (const float*)d_in[1];
  const float* W1    = (const float*)d_in[2];
  const float* b1    = (const float*)d_in[3];
  const float* gamma = (const float*)d_in[4];
  const float* beta  = (const float*)d_in[5];
  const float* w2    = (const float*)d_in[6];
  const float* b2    = (const float*)d_in[7];
  float* ws  = (float*)d_ws;
  float* out = (float*)d_out;
  (void)in_sizes; (void)n_in; (void)out_size; (void)ws_size;

  hipLaunchKernelGGL(k0_gemm,    dim3(512),  dim3(256), 0, stream, img, txt, W1, b1, ws);
  hipLaunchKernelGGL(k_conv2,    dim3(2048), dim3(256), 0, stream, ws);
  hipLaunchKernelGGL(k1_stats,   dim3(1024), dim3(256), 0, stream, ws, gamma, beta, w2);
  hipLaunchKernelGGL(k2_mfma,    dim3(512),  dim3(256), 0, stream, ws);
  hipLaunchKernelGGL(k3_score,   dim3(1024), dim3(256), 0, stream, ws);
  hipLaunchKernelGGL(k4_combine, dim3(1024), dim3(256), 0, stream, ws, img, txt, b2, out);
}

// Round 10
// 187.141 us; speedup vs baseline: 1.0298x; 1.0298x over previous
//
#include <hip/hip_runtime.h>
#include <math.h>

// DynamicRelationModeler: x=concat(img,txt) [512x512]; per r: a=x@Wl_r^T, b=x@Wr_r^T;
// h=a_i+b_j+b1_r; LN over H; s=relu(hn)@w2_r+b2_r; argmax/max over r; mask.
//
// Round-10: conv2 fused into k0's epilogue (k0 holds every a/b value in
// registers at write-out -> emit fp32 plane AND bf16 hi/lo planes directly;
// bit-identical to r9's conv2). Chain is now 5 kernels:
//   k0(+conv) -> k1 -> k2_mfma -> k3 -> k4
// Diagnostic: if the total does NOT drop by conv2's cost (+ one launch gap),
// the unaccounted ~50us is a fixed overhead floor -> pivot to deeper fusion.
// K1/K2m/K3/K4 byte-identical to round 9 (passing).
//
// ws layout (floats):
//   Aarr [4][512][512]  a_r[i][h]            (OFF_A)
//   Barr [4][512][512]  b'_r[j][h]           (OFF_B)
//   dotp [2][4][512][512]  k-split dots      (OFF_DOT)
//   Spart[2][4][512][512]  k-split scores    (OFF_S)
//   ma/qa/mb/qb [4][512], G, BW, SA, SB, CB  (tail)
// Alias (live range disjoint, stream-ordered):
//   AH/AL/BH/BL [4][512][512] ush @ OFF_S    (k0 .. k2_mfma; k3 overwrites)

typedef __attribute__((ext_vector_type(8))) short s8b;            // 8 x bf16
typedef __attribute__((ext_vector_type(4))) float f32x4;
typedef __attribute__((ext_vector_type(4))) unsigned short us4;

namespace {
constexpr size_t PLANE  = 512 * 512;            // 262144
constexpr size_t OFF_A   = 0;
constexpr size_t OFF_B   = OFF_A + 4 * PLANE;   // 1048576
constexpr size_t OFF_DOT = OFF_B + 4 * PLANE;   // 2097152
constexpr size_t OFF_S   = OFF_DOT + 8 * PLANE; // 4194304
constexpr size_t OFF_MA  = OFF_S + 8 * PLANE;   // 6291456
constexpr size_t OFF_QA  = OFF_MA + 2048;
constexpr size_t OFF_MB  = OFF_QA + 2048;
constexpr size_t OFF_QB  = OFF_MB + 2048;
constexpr size_t OFF_G   = OFF_QB + 2048;       // gamma [2048]
constexpr size_t OFF_BW  = OFF_G + 2048;        // (beta, w2/2) [2048][2]
constexpr size_t OFF_SA  = OFF_BW + 4096;       // [2048]
constexpr size_t OFF_SB  = OFF_SA + 2048;       // [2048]
constexpr size_t OFF_CB  = OFF_SB + 2048;       // [4]  (ws end: same as r5)
}

__device__ __forceinline__ unsigned short bf16rne(float v) {
  const unsigned u = __float_as_uint(v);
  return (unsigned short)((u + 0x7fffu + ((u >> 16) & 1u)) >> 16);
}

__device__ __forceinline__ f32x4 mfma16(s8b a, s8b b, f32x4 c) {
  return __builtin_amdgcn_mfma_f32_16x16x32_bf16(a, b, c, 0, 0, 0);
}

// ---------------- K0: input GEMM  C[n][4096] = x @ [Wl|Wr]^T  (+bf16 split) ----------------
// grid 512 = 8 i-tiles x 64 col-tiles; block 256 (16x16 threads, 4x4 reg tile)
// fp32-exact output (argmax-critical) + fused hi/lo bf16 plane emission
// (replaces the separate conv2 kernel; identical bf16rne math).
__global__ __launch_bounds__(256) void k0_gemm(const float* __restrict__ img,
                                               const float* __restrict__ txt,
                                               const float* __restrict__ W1,
                                               const float* __restrict__ b1,
                                               float* __restrict__ ws) {
  const int b = blockIdx.x;
  const int it = b >> 6;
  const int ct = b & 63;
  const int which = ct >> 5;      // 0 -> a (Wl), 1 -> b (Wr)
  const int r = (ct >> 3) & 3;
  const int ht = ct & 7;
  const int i0 = it << 6, h0 = ht << 6;
  const int t = threadIdx.x;
  const int tx = t & 15, ty = t >> 4;

  __shared__ float Xs[16 * 68];   // [k][i], pitch 68 -> 16B-aligned rows for b128 reads
  __shared__ float Wsm[16 * 68];  // [k][h]

  float acc[16], pacc[16];
#pragma unroll
  for (int p = 0; p < 16; ++p) { acc[p] = 0.f; pacc[p] = 0.f; }

  const int srow = t >> 2;
  const int sf4 = (t & 3) << 2;
  const int xi = i0 + srow;
  const float* xrow = (xi < 256) ? (img + (size_t)xi * 512)
                                 : (txt + (size_t)(xi - 256) * 512);
  const float* wrow = W1 + (size_t)(r * 512 + h0 + srow) * 1024 + which * 512;

  for (int k0 = 0; k0 < 512; k0 += 16) {
    const float4 xv = *(const float4*)(xrow + k0 + sf4);
    const float4 wv = *(const float4*)(wrow + k0 + sf4);
    __syncthreads();
    Xs[(sf4 + 0) * 68 + srow] = xv.x;
    Xs[(sf4 + 1) * 68 + srow] = xv.y;
    Xs[(sf4 + 2) * 68 + srow] = xv.z;
    Xs[(sf4 + 3) * 68 + srow] = xv.w;
    Wsm[(sf4 + 0) * 68 + srow] = wv.x;
    Wsm[(sf4 + 1) * 68 + srow] = wv.y;
    Wsm[(sf4 + 2) * 68 + srow] = wv.z;
    Wsm[(sf4 + 3) * 68 + srow] = wv.w;
    __syncthreads();
#pragma unroll
    for (int k = 0; k < 16; ++k) {
      const float4 a4 = *(const float4*)&Xs[k * 68 + 4 * ty];
      const float4 b4 = *(const float4*)&Wsm[k * 68 + 4 * tx];
      const float av[4] = {a4.x, a4.y, a4.z, a4.w};
      const float bv[4] = {b4.x, b4.y, b4.z, b4.w};
#pragma unroll
      for (int c = 0; c < 4; ++c)
#pragma unroll
        for (int d = 0; d < 4; ++d)
          pacc[c * 4 + d] = fmaf(av[c], bv[d], pacc[c * 4 + d]);
    }
    // fold per-stage partial into master (split accumulation: ~1e-7 error)
#pragma unroll
    for (int p = 0; p < 16; ++p) { acc[p] += pacc[p]; pacc[p] = 0.f; }
  }

  float4 bb = make_float4(0.f, 0.f, 0.f, 0.f);
  if (which) bb = *(const float4*)(b1 + r * 512 + h0 + 4 * tx);
  float* dst = ws + (which ? OFF_B : OFF_A) + (size_t)r * PLANE;
  // fused conv2: bf16 hi/lo planes for K2's MFMA, aliased @ OFF_S
  unsigned short* SHb = (unsigned short*)(ws + OFF_S) + (which ? 8 * PLANE : 0);
#pragma unroll
  for (int c = 0; c < 4; ++c) {
    float4 v;
    v.x = acc[c * 4 + 0] + bb.x;
    v.y = acc[c * 4 + 1] + bb.y;
    v.z = acc[c * 4 + 2] + bb.z;
    v.w = acc[c * 4 + 3] + bb.w;
    const size_t e = (size_t)r * PLANE + (size_t)(i0 + 4 * ty + c) * 512 + h0 + 4 * tx;
    *(float4*)(ws + (which ? OFF_B : OFF_A) + e) = v;
    const float vv[4] = {v.x, v.y, v.z, v.w};
    us4 h4, l4;
#pragma unroll
    for (int q = 0; q < 4; ++q) {
      const unsigned short hh = bf16rne(vv[q]);
      h4[q] = hh;
      l4[q] = bf16rne(vv[q] - __uint_as_float(((unsigned)hh) << 16));
    }
    *(us4*)(SHb + e) = h4;
    *(us4*)(SHb + 4 * PLANE + e) = l4;
  }
  (void)dst;
}

// ---------------- K1: row stats + relu-linear row sums + packing ----------------
// one wave per (which, r, row); grid 1024 x 256.  (unchanged from r5)
__global__ __launch_bounds__(256) void k1_stats(float* __restrict__ ws,
                                                const float* __restrict__ gamma,
                                                const float* __restrict__ beta,
                                                const float* __restrict__ w2) {
  const int t = threadIdx.x;
  const int gw = (blockIdx.x * 256 + t) >> 6;  // 0..4095
  const int lane = t & 63;
  const int which = gw >> 11;
  const int rr = (gw >> 9) & 3;
  const int row = gw & 511;
  const float* src =
      ws + (which ? OFF_B : OFF_A) + (size_t)(rr * 512 + row) * 512 + lane * 8;
  const float* gsrc = gamma + rr * 512 + lane * 8;
  const float* wsrc = w2 + rr * 512 + lane * 8;
  float s = 0.f, q = 0.f, sa = 0.f, cgs = 0.f;
#pragma unroll
  for (int c = 0; c < 2; ++c) {
    const float4 v = *(const float4*)(src + c * 4);
    const float4 g = *(const float4*)(gsrc + c * 4);
    const float4 w = *(const float4*)(wsrc + c * 4);
    s += v.x + v.y + v.z + v.w;
    q += v.x * v.x + v.y * v.y + v.z * v.z + v.w * v.w;
    const float cgx = 0.5f * w.x * g.x;
    const float cgy = 0.5f * w.y * g.y;
    const float cgz = 0.5f * w.z * g.z;
    const float cgw = 0.5f * w.w * g.w;
    sa += cgx * v.x + cgy * v.y + cgz * v.z + cgw * v.w;
    cgs += cgx + cgy + cgz + cgw;
  }
#pragma unroll
  for (int off = 32; off >= 1; off >>= 1) {
    s += __shfl_down(s, off, 64);
    q += __shfl_down(q, off, 64);
    sa += __shfl_down(sa, off, 64);
    cgs += __shfl_down(cgs, off, 64);
  }
  if (lane == 0) {
    const float ma = s * (1.f / 512.f);
    ws[(which ? OFF_MB : OFF_MA) + rr * 512 + row] = ma;
    ws[(which ? OFF_QB : OFF_QA) + rr * 512 + row] = q;
    ws[(which ? OFF_SB : OFF_SA) + rr * 512 + row] = sa - ma * cgs;
  }
  if (blockIdx.x < 8) {
    const int idx = blockIdx.x * 256 + t;  // 0..2047 == r*512+k
    ws[OFF_G + idx] = gamma[idx];
    float2 bw;
    bw.x = beta[idx];
    bw.y = 0.5f * w2[idx];    // c = w2/2
    *(float2*)(ws + OFF_BW + (size_t)idx * 2) = bw;
  }
  if (blockIdx.x == 8) {
    const int rb = t >> 6;   // 0..3
    float cb = 0.f;
#pragma unroll
    for (int c = 0; c < 8; ++c)
      cb += 0.5f * w2[rb * 512 + lane * 8 + c] * beta[rb * 512 + lane * 8 + c];
#pragma unroll
    for (int off = 32; off >= 1; off >>= 1) cb += __shfl_down(cb, off, 64);
    if (lane == 0) ws[OFF_CB + rb] = cb;
  }
}

// ---------------- K2 (MFMA): dotp[ks][r][i][j] = sum_k a.b' ----------------
// grid 512 = 8jt x 8it x 4r x 2ks; block 256 = 4 waves, each wave 32x32.
// Split-bf16, 3 products; dot error ~2e-4 -> Sv rel err ~4e-7 (argmax-safe, r9).
__global__ __launch_bounds__(256) void k2_mfma(float* __restrict__ ws) {
  const int b = blockIdx.x;
  const int jt = b & 7, it = (b >> 3) & 7, r = (b >> 6) & 3, ks = b >> 8;
  const int i0 = it << 6, j0 = jt << 6;
  const int kb = ks << 8;
  const int t = threadIdx.x, w = t >> 6, l = t & 63;
  const int wr = w >> 1, wc = w & 1;
  const int lrow = l & 15, lk = (l >> 4) << 3;

  const unsigned short* SH = (const unsigned short*)(ws + OFF_S);
  const unsigned short* AH = SH;
  const unsigned short* AL = SH + 4 * PLANE;
  const unsigned short* BH = SH + 8 * PLANE;
  const unsigned short* BL = SH + 12 * PLANE;

  const int ia = i0 + wr * 32 + lrow;
  const int jb = j0 + wc * 32 + lrow;
  const size_t ar0 = (size_t)(r * 512 + ia) * 512 + kb + lk;
  const size_t ar1 = ar0 + 16 * 512;
  const size_t br0 = (size_t)(r * 512 + jb) * 512 + kb + lk;
  const size_t br1 = br0 + 16 * 512;

  f32x4 acc00 = {0.f, 0.f, 0.f, 0.f}, acc01 = acc00, acc10 = acc00, acc11 = acc00;

#pragma unroll
  for (int k0 = 0; k0 < 256; k0 += 32) {
    const s8b ah0 = *(const s8b*)(AH + ar0 + k0);
    const s8b ah1 = *(const s8b*)(AH + ar1 + k0);
    const s8b al0 = *(const s8b*)(AL + ar0 + k0);
    const s8b al1 = *(const s8b*)(AL + ar1 + k0);
    const s8b bh0 = *(const s8b*)(BH + br0 + k0);
    const s8b bh1 = *(const s8b*)(BH + br1 + k0);
    const s8b bl0 = *(const s8b*)(BL + br0 + k0);
    const s8b bl1 = *(const s8b*)(BL + br1 + k0);
    acc00 = mfma16(ah0, bh0, acc00);
    acc00 = mfma16(ah0, bl0, acc00);
    acc00 = mfma16(al0, bh0, acc00);
    acc01 = mfma16(ah0, bh1, acc01);
    acc01 = mfma16(ah0, bl1, acc01);
    acc01 = mfma16(al0, bh1, acc01);
    acc10 = mfma16(ah1, bh0, acc10);
    acc10 = mfma16(ah1, bl0, acc10);
    acc10 = mfma16(al1, bh0, acc10);
    acc11 = mfma16(ah1, bh1, acc11);
    acc11 = mfma16(ah1, bl1, acc11);
    acc11 = mfma16(al1, bh1, acc11);
  }

  float* dst = ws + OFF_DOT + (size_t)ks * (4 * PLANE) + (size_t)r * PLANE;
  const int rb = i0 + wr * 32 + ((l >> 4) << 2);
  const int cb = j0 + wc * 32 + lrow;
#pragma unroll
  for (int v = 0; v < 4; ++v) {
    dst[(size_t)(rb + v) * 512 + cb]           = acc00[v];
    dst[(size_t)(rb + v) * 512 + cb + 16]      = acc01[v];
    dst[(size_t)(rb + 16 + v) * 512 + cb]      = acc10[v];
    dst[(size_t)(rb + 16 + v) * 512 + cb + 16] = acc11[v];
  }
}

// ---------------- K3: score kernel v6 (abs-trick, 3-op inner) ----------------
// (unchanged from r5)
__global__ __launch_bounds__(256) void k3_score(float* __restrict__ ws) {
  const int b = blockIdx.x;
  const int jt = b & 15, it = (b >> 4) & 7, r = (b >> 7) & 3, ks = b >> 9;
  const int i0 = it << 6, j0 = jt << 5;
  const int t = threadIdx.x;
  const int tx = t & 15, ty = t >> 4;

  __shared__ float As2[64 * 68];  // [k][i-row swizzled], 64 rows, pitch 68
  __shared__ float Bs2[64 * 36];  // [k][j-row swizzled], 32 rows, pitch 36
  __shared__ float bwS[64 * 2];   // (beta, c) per k of current chunk

  const float4 mav = *(const float4*)(ws + OFF_MA + r * 512 + i0 + 4 * ty);
  const float4 qav = *(const float4*)(ws + OFF_QA + r * 512 + i0 + 4 * ty);
  const float2 mbv = *(const float2*)(ws + OFF_MB + r * 512 + j0 + 2 * tx);
  const float2 qbv = *(const float2*)(ws + OFF_QB + r * 512 + j0 + 2 * tx);
  const float4 sav = *(const float4*)(ws + OFF_SA + r * 512 + i0 + 4 * ty);
  const float2 sbv = *(const float2*)(ws + OFF_SB + r * 512 + j0 + 2 * tx);
  const float cbr = ws[OFF_CB + r];
  const float mavA[4] = {mav.x, mav.y, mav.z, mav.w};
  const float qavA[4] = {qav.x, qav.y, qav.z, qav.w};
  const float savA[4] = {sav.x, sav.y, sav.z, sav.w};
  const float mbA[2] = {mbv.x, mbv.y};
  const float qbA[2] = {qbv.x, qbv.y};
  const float sbA[2] = {sbv.x, sbv.y};
  float Sv[8], acc[8];
#pragma unroll
  for (int c = 0; c < 4; ++c) {
    const size_t doff = (size_t)r * PLANE + (size_t)(i0 + 4 * ty + c) * 512 + j0 + 2 * tx;
    const float2 d0 = *(const float2*)(ws + OFF_DOT + doff);
    const float2 d1 = *(const float2*)(ws + OFF_DOT + 4 * PLANE + doff);
    const float dA[2] = {d0.x + d1.x, d0.y + d1.y};
#pragma unroll
    for (int d = 0; d < 2; ++d) {
      const int p = c * 2 + d;
      const float mu = mavA[c] + mbA[d];
      const float msq = (qavA[c] + qbA[d] + 2.f * dA[d]) * (1.f / 512.f);
      const float var = msq - mu * mu;
      Sv[p] = 1.0f / sqrtf(var + 1e-5f);   // precise (no fast-math)
      acc[p] = (ks == 0) ? fmaf(Sv[p], savA[c] + sbA[d], cbr) : 0.f;
    }
  }

  const int kbase = ks << 8;
  const int srow = ty;              // 0..15
  const int sf4 = tx << 2;          // 0..60; (k>>2)&7 == tx&7 for staged k
  const int sblk = tx & 7;
  float maR[4], mbR[2];
#pragma unroll
  for (int c2 = 0; c2 < 4; ++c2)
    maR[c2] = ws[OFF_MA + r * 512 + i0 + srow + 16 * c2];
#pragma unroll
  for (int c2 = 0; c2 < 2; ++c2)
    mbR[c2] = ws[OFF_MB + r * 512 + j0 + srow + 16 * c2];

  float4 aC[4], bC[2], gC;
  float2 bwC = make_float2(0.f, 0.f);
  {
    const int kb = kbase;
    gC = *(const float4*)(ws + OFF_G + r * 512 + kb + sf4);
#pragma unroll
    for (int c2 = 0; c2 < 4; ++c2)
      aC[c2] = *(const float4*)(ws + OFF_A + (size_t)(r * 512 + i0 + srow + 16 * c2) * 512 + kb + sf4);
#pragma unroll
    for (int c2 = 0; c2 < 2; ++c2)
      bC[c2] = *(const float4*)(ws + OFF_B + (size_t)(r * 512 + j0 + srow + 16 * c2) * 512 + kb + sf4);
    if (t < 64) bwC = *(const float2*)(ws + OFF_BW + (size_t)(r * 512 + kb + t) * 2);
  }

#pragma unroll
  for (int kc = 0; kc < 4; ++kc) {
    __syncthreads();  // previous chunk's LDS reads complete before overwrite
    {
      const float ga[4] = {gC.x, gC.y, gC.z, gC.w};
#pragma unroll
      for (int c2 = 0; c2 < 4; ++c2) {
        const int row = srow + 16 * c2;
        const int off = (((row >> 2) ^ sblk) << 2) + (row & 3);
        const float aq[4] = {aC[c2].x, aC[c2].y, aC[c2].z, aC[c2].w};
#pragma unroll
        for (int q = 0; q < 4; ++q)
          As2[(sf4 + q) * 68 + off] = (aq[q] - maR[c2]) * ga[q];
      }
#pragma unroll
      for (int c2 = 0; c2 < 2; ++c2) {
        const int row = srow + 16 * c2;
        const int off = (((row >> 2) ^ sblk) << 2) + (row & 3);
        const float bq[4] = {bC[c2].x, bC[c2].y, bC[c2].z, bC[c2].w};
#pragma unroll
        for (int q = 0; q < 4; ++q)
          Bs2[(sf4 + q) * 36 + off] = (bq[q] - mbR[c2]) * ga[q];
      }
      if (t < 64) *(float2*)(bwS + 2 * t) = bwC;
    }
    if (kc < 3) {
      const int kb = kbase + ((kc + 1) << 6);
      gC = *(const float4*)(ws + OFF_G + r * 512 + kb + sf4);
#pragma unroll
      for (int c2 = 0; c2 < 4; ++c2)
        aC[c2] = *(const float4*)(ws + OFF_A + (size_t)(r * 512 + i0 + srow + 16 * c2) * 512 + kb + sf4);
#pragma unroll
      for (int c2 = 0; c2 < 2; ++c2)
        bC[c2] = *(const float4*)(ws + OFF_B + (size_t)(r * 512 + j0 + srow + 16 * c2) * 512 + kb + sf4);
      if (t < 64) bwC = *(const float2*)(ws + OFF_BW + (size_t)(r * 512 + kb + t) * 2);
    }
    __syncthreads();  // staged data visible

    float cacc[8];
#pragma unroll
    for (int p = 0; p < 8; ++p) cacc[p] = 0.f;

#pragma unroll 4
    for (int k = 0; k < 64; ++k) {
      const int K = (k >> 2) & 7;
      const float4 aA = *(const float4*)&As2[k * 68 + ((ty ^ K) << 2)];  // b128
      const float2 bB = *(const float2*)&Bs2[k * 36 + (((tx >> 1) ^ K) << 2) + ((tx & 1) << 1)];  // b64
      const float2 bw = *(const float2*)&bwS[2 * k];                     // b64 broadcast
      const float aq[4] = {aA.x, aA.y, aA.z, aA.w};
      const float bq[2] = {bB.x, bB.y};
#pragma unroll
      for (int c = 0; c < 4; ++c)
#pragma unroll
        for (int d = 0; d < 2; ++d) {
          const int p = c * 2 + d;
          const float u = aq[c] + bq[d];               // (a-ma)g + (b-mb)g
          const float hn = fmaf(u, Sv[p], bw.x);       // *Sv + beta
          cacc[p] = fmaf(bw.y, fabsf(hn), cacc[p]);    // += c*|hn|  (abs free)
        }
    }
#pragma unroll
    for (int p = 0; p < 8; ++p) acc[p] += cacc[p];
  }

  float* dst = ws + OFF_S + (size_t)ks * (4 * PLANE) + (size_t)r * PLANE;
#pragma unroll
  for (int c = 0; c < 4; ++c) {
    float2 v;
    v.x = acc[c * 2 + 0];
    v.y = acc[c * 2 + 1];
    *(float2*)(dst + (size_t)(i0 + 4 * ty + c) * 512 + j0 + 2 * tx) = v;
  }
}

// ---------------- K4: combine + outputs ---------------- (unchanged)
__global__ __launch_bounds__(256) void k4_combine(const float* __restrict__ ws,
                                                  const float* __restrict__ img,
                                                  const float* __restrict__ txt,
                                                  const float* __restrict__ b2,
                                                  float* __restrict__ out) {
  const int idx = blockIdx.x * 256 + threadIdx.x;  // 0..262143
  const int i = idx >> 9, j = idx & 511;
  const float* s0 = ws + OFF_S;
  const float* s1 = ws + OFF_S + 4 * PLANE;
  float best = -3.4e38f;
  int rel = 0;
#pragma unroll
  for (int r = 0; r < 4; ++r) {
    const float s = s0[r * PLANE + idx] + s1[r * PLANE + idx] + b2[r];
    if (s > best) { best = s; rel = r; }  // strict > == first-index argmax
  }
  out[idx] = (i < 256) ? img[idx] : txt[idx - 131072];
  out[PLANE + idx] = best;
  out[2 * PLANE + idx] = (float)rel;
  // match numpy: float32 best promoted to double vs python-float 0.2
  out[3 * PLANE + idx] = (i != j && (double)best > 0.2) ? 1.0f : 0.0f;
}

extern "C" void kernel_launch(void* const* d_in, const int* in_sizes, int n_in,
                              void* d_out, int out_size, void* d_ws, size_t ws_size,
                              hipStream_t stream) {
  const float* img   = (const float*)d_in[0];
  const float* txt   = (const float*)d_in[1];
  const float* W1    = (const float*)d_in[2];
  const float* b1    = (const float*)d_in[3];
  const float* gamma = (const float*)d_in[4];
  const float* beta  = (const float*)d_in[5];
  const float* w2    = (const float*)d_in[6];
  const float* b2    = (const float*)d_in[7];
  float* ws  = (float*)d_ws;
  float* out = (float*)d_out;
  (void)in_sizes; (void)n_in; (void)out_size; (void)ws_size;

  hipLaunchKernelGGL(k0_gemm,    dim3(512),  dim3(256), 0, stream, img, txt, W1, b1, ws);
  hipLaunchKernelGGL(k1_stats,   dim3(1024), dim3(256), 0, stream, ws, gamma, beta, w2);
  hipLaunchKernelGGL(k2_mfma,    dim3(512),  dim3(256), 0, stream, ws);
  hipLaunchKernelGGL(k3_score,   dim3(1024), dim3(256), 0, stream, ws);
  hipLaunchKernelGGL(k4_combine, dim3(1024), dim3(256), 0, stream, ws, img, txt, b2, out);
}